// Round 6
// baseline (63727.594 us; speedup 1.0000x reference)
//
#include <hip/hip_runtime.h>

#define NPTS 288
#define DIMS 2048
#define KC   6
#define N_IT 25
#define BLK  1024
#define NSL  4              // dim-slices per batch (1 block each)
#define SLD  (DIMS / NSL)   // 512 dims per slice
#define TD   64             // dims per tile
#define NT   (SLD / TD)     // 8 tiles per slice
#define TP   66             // tile row stride in words ([j][d] layout)

// ---------------- K0: init centers = first KC points ----------------
__global__ __launch_bounds__(BLK) void k_init(const float* __restrict__ x,
                                              float* __restrict__ cent) {
  const int b = blockIdx.x >> 2, s = blockIdx.x & 3;
  const int t = threadIdx.x;
  const float* __restrict__ Mb = x + (size_t)b * (DIMS * NPTS);
#pragma unroll
  for (int i = 0; i < 3; ++i) {
    const int e  = t + BLK * i;      // 0..3071 = KC*SLD
    const int k  = e >> 9;
    const int cl = e & (SLD - 1);
    const int c  = s * SLD + cl;
    cent[((size_t)b * KC + k) * DIMS + c] = Mb[(size_t)c * NPTS + k];
  }
}

// ---------------- K1: dots for the INITIAL centers (prologue only) ----------------
__global__ __launch_bounds__(BLK) void k_dots(const float* __restrict__ x,
                                              const float* __restrict__ cent,
                                              float* __restrict__ part,
                                              float* __restrict__ csqp) {
  const int b = blockIdx.x >> 2, s = blockIdx.x & 3;
  const int t = threadIdx.x, wv = t >> 6, lane = t & 63;
  const float* __restrict__ Mb = x + (size_t)b * (DIMS * NPTS);
  const float* __restrict__ cb = cent + (size_t)b * (KC * DIMS);

  __shared__ __attribute__((aligned(16))) float cs[KC][SLD];
  __shared__ float part_l[3][KC][NPTS];
#pragma unroll
  for (int i = 0; i < 3; ++i) {
    const int e = t + BLK * i;
    const int k = e >> 9, cl = e & (SLD - 1);
    cs[k][cl] = cb[(size_t)k * DIMS + s * SLD + cl];
  }
  __syncthreads();

  if (wv < 15) {
    const int g = wv / 5;
    const int q = t - g * 320;
    if (q < NPTS) {
      const int c0 = (g == 0) ? 0   : (g == 1 ? 172 : 344);
      const int c1 = (g == 0) ? 172 : (g == 1 ? 344 : 512);
      float acc[KC];
#pragma unroll
      for (int k = 0; k < KC; ++k) acc[k] = 0.f;
      const float* __restrict__ pb = Mb + (size_t)(s * SLD) * NPTS + q;
#pragma unroll 2
      for (int c = c0; c < c1; c += 4) {
        const float p0 = pb[(size_t)(c + 0) * NPTS];
        const float p1 = pb[(size_t)(c + 1) * NPTS];
        const float p2 = pb[(size_t)(c + 2) * NPTS];
        const float p3 = pb[(size_t)(c + 3) * NPTS];
#pragma unroll
        for (int k = 0; k < KC; ++k) {
          const float4 cv = *(const float4*)&cs[k][c];
          acc[k] += p0 * cv.x + p1 * cv.y + p2 * cv.z + p3 * cv.w;
        }
      }
#pragma unroll
      for (int k = 0; k < KC; ++k) part_l[g][k][q] = acc[k];
    }
  } else {
    float a[KC];
#pragma unroll
    for (int k = 0; k < KC; ++k) a[k] = 0.f;
#pragma unroll
    for (int i = 0; i < SLD / 64; ++i) {
#pragma unroll
      for (int k = 0; k < KC; ++k) {
        const float v = cs[k][lane + 64 * i];
        a[k] += v * v;
      }
    }
#pragma unroll
    for (int k = 0; k < KC; ++k) {
#pragma unroll
      for (int off = 32; off; off >>= 1) a[k] += __shfl_xor(a[k], off, 64);
    }
    if (lane == 0) {
#pragma unroll
      for (int k = 0; k < KC; ++k)
        csqp[(size_t)(b * NSL + s) * KC + k] = a[k];
    }
  }
  __syncthreads();

  if (t < NPTS) {
#pragma unroll
    for (int k = 0; k < KC; ++k)
      part[((size_t)(b * NSL + s) * KC + k) * NPTS + t] =
          part_l[0][k][t] + part_l[1][k][t] + part_l[2][k][t];
  }
}

// ---------------- K2: fully-fused iteration, ONE sweep of x ----------------
// per 64-dim tile: stage (prefetched) -> sums(old assign) -> update cs -> dots partial
// __launch_bounds__(1024, 4): 4 waves/EU == our 1 block/CU (LDS-limited anyway)
// -> VGPR cap 128, not 64. Round-5's default (8 waves/EU assumed) capped at 64
// and spilled the ~90-value live set to scratch: 4.7 GB HBM writes/dispatch.
__global__ __launch_bounds__(BLK, 4) void k_iter(const float* __restrict__ x,
                                                 float* __restrict__ cent,
                                                 float* __restrict__ part,
                                                 float* __restrict__ csqp,
                                                 int do_dots) {
  const int b = blockIdx.x >> 2, s = blockIdx.x & 3;
  const int t = threadIdx.x, wv = t >> 6, lane = t & 63;
  const float* __restrict__ Mb = x + (size_t)b * (DIMS * NPTS);
  float* __restrict__ cb = cent + (size_t)b * (KC * DIMS);

  __shared__ __attribute__((aligned(16))) float cs[KC][SLD];   // 12,288 B
  __shared__ float tile[NPTS * TP];                            // 76,032 B  [j][d] stride 66
  __shared__ float pool[KC][TD][17];                           // 26,112 B  (exchange buf after loop)
  __shared__ __attribute__((aligned(16))) int assign_s[NPTS];  // 1,152 B
  __shared__ float csqh[KC];
  __shared__ int cnt_i[KC];

  float* exbuf = &pool[0][0][0];   // [NPTS][KC] after tile loop

  // ---- issue prefetch of tile 0 immediately (hides under argmin phase) ----
  float pre[18];
  {
    const float* __restrict__ src = Mb + (size_t)(s * SLD) * NPTS;   // dt = 0, linear
#pragma unroll
    for (int i = 0; i < 18; ++i) pre[i] = src[t + BLK * i];
  }

  // old centers slice -> LDS
#pragma unroll
  for (int i = 0; i < 3; ++i) {
    const int e = t + BLK * i;
    const int k = e >> 9, cl = e & (SLD - 1);
    cs[k][cl] = cb[(size_t)k * DIMS + s * SLD + cl];
  }

  // ---- argmin phase (redundant per slice-block; fixed order = deterministic) ----
  if (t < KC) {
    const float* pc = csqp + (size_t)b * NSL * KC + t;
    csqh[t] = 0.5f * (pc[0] + pc[KC] + pc[2 * KC] + pc[3 * KC]);
    cnt_i[t] = 0;
  }
  __syncthreads();

  int myA = -1;
  if (t < NPTS) {
    const float* pp = part + (size_t)b * NSL * KC * NPTS + t;
    float best = 0.f;
    int bi = 0;
#pragma unroll
    for (int k = 0; k < KC; ++k) {
      const float S = pp[(size_t)k * NPTS] + pp[(size_t)(KC + k) * NPTS] +
                      pp[(size_t)(2 * KC + k) * NPTS] + pp[(size_t)(3 * KC + k) * NPTS];
      const float sc = csqh[k] - S;     // argmin_k(d) == argmin_k(csq/2 - S)
      if (k == 0 || sc < best) { best = sc; bi = k; }
    }
    assign_s[t] = bi;
    myA = bi;
  }
  if (t < 320) {   // waves 0..4, uniform per-wave predicate
#pragma unroll
    for (int k = 0; k < KC; ++k) {
      unsigned long long m = __ballot(myA == k);
      if (lane == 0) atomicAdd(&cnt_i[k], (int)__popcll(m));
    }
  }
  __syncthreads();   // assign + counts ready

  // hoist this wave's 18 point-assignments into SGPRs
  int aj[18];
#pragma unroll
  for (int r = 0; r < 18; ++r)
    aj[r] = __builtin_amdgcn_readfirstlane(assign_s[wv * 18 + r]);

  // dots state: waves 0-4 <-> points x dims[0,32); waves 5-9 <-> points x dims[32,64)
  const int grp  = wv / 5;                 // 0,1 active; 2,3 idle in dots
  const int dq   = t - grp * 320;          // point index for grp<2
  const bool dact = (wv < 10) && (dq < NPTS);
  float acc[KC];
#pragma unroll
  for (int k = 0; k < KC; ++k) acc[k] = 0.f;

  // ---- tile loop: ONE pass over x ----
  for (int dt = 0; dt < NT; ++dt) {
    __syncthreads();                       // (A) tile free (prev dots done reading)
#pragma unroll
    for (int i = 0; i < 18; ++i) {         // regs -> tile  [j][d] stride 66
      const int e = t + BLK * i;
      const int d = e / NPTS, j = e - d * NPTS;
      tile[j * TP + d] = pre[i];
    }
    __syncthreads();                       // (B) tile ready

    if (dt + 1 < NT) {                     // issue next-tile loads (hide under compute)
      const float* __restrict__ src = Mb + (size_t)(s * SLD + (dt + 1) * TD) * NPTS;
#pragma unroll
      for (int i = 0; i < 18; ++i) pre[i] = src[t + BLK * i];
    }

    // sums: lane <-> dim, wave <-> 18 points; scalar branch on SGPR assignment
    {
      float s0 = 0, s1 = 0, s2 = 0, s3 = 0, s4 = 0, s5 = 0;
      const int jb = wv * 18;
#pragma unroll
      for (int r = 0; r < 18; ++r) {
        const float p = tile[(jb + r) * TP + lane];
        const int a = aj[r];
        if      (a == 0) s0 += p;
        else if (a == 1) s1 += p;
        else if (a == 2) s2 += p;
        else if (a == 3) s3 += p;
        else if (a == 4) s4 += p;
        else             s5 += p;
      }
      pool[0][lane][wv] = s0; pool[1][lane][wv] = s1; pool[2][lane][wv] = s2;
      pool[3][lane][wv] = s3; pool[4][lane][wv] = s4; pool[5][lane][wv] = s5;
    }
    __syncthreads();                       // (C) pool ready

    if (t < KC * TD) {                     // 384 threads: reduce 16 waves, update cs
      const int k = t >> 6, d = t & 63;
      float sum = 0.f;
#pragma unroll
      for (int w = 0; w < 16; ++w) sum += pool[k][d][w];   // fixed order
      const int cn = cnt_i[k];
      const int cl = dt * TD + d;
      cs[k][cl] = (cn > 0) ? (sum / (float)cn) : cs[k][cl];
    }
    __syncthreads();                       // (D) new cs for this tile ready

    // dots partial for these 64 dims from the SAME tile (new centers)
    if (do_dots && dact) {
      const int base = dq * TP + grp * 32;
      const int cbase = dt * TD + grp * 32;
#pragma unroll
      for (int db = 0; db < 8; ++db) {
        const float2 p01 = *(const float2*)&tile[base + db * 4];
        const float2 p23 = *(const float2*)&tile[base + db * 4 + 2];
#pragma unroll
        for (int k = 0; k < KC; ++k) {
          const float4 cv = *(const float4*)&cs[k][cbase + db * 4];  // uniform broadcast
          acc[k] += p01.x * cv.x + p01.y * cv.y + p23.x * cv.z + p23.y * cv.w;
        }
      }
    }
  }

  // store new centers (next dispatch + final output read them)
#pragma unroll
  for (int i = 0; i < 3; ++i) {
    const int e = t + BLK * i;
    const int k = e >> 9, cl = e & (SLD - 1);
    cb[(size_t)k * DIMS + s * SLD + cl] = cs[k][cl];
  }

  if (do_dots) {
    __syncthreads();                       // dots done; pool area free for exchange
    if (wv >= 5 && wv < 10 && dq < NPTS) {
#pragma unroll
      for (int k = 0; k < KC; ++k) exbuf[dq * KC + k] = acc[k];
    }
    if (wv == 15) {
      // csq of the NEW centers
      float a[KC];
#pragma unroll
      for (int k = 0; k < KC; ++k) a[k] = 0.f;
#pragma unroll
      for (int i = 0; i < SLD / 64; ++i) {
#pragma unroll
        for (int k = 0; k < KC; ++k) {
          const float v = cs[k][lane + 64 * i];
          a[k] += v * v;
        }
      }
#pragma unroll
      for (int k = 0; k < KC; ++k) {
#pragma unroll
        for (int off = 32; off; off >>= 1) a[k] += __shfl_xor(a[k], off, 64);
      }
      if (lane == 0) {
#pragma unroll
        for (int k = 0; k < KC; ++k)
          csqp[(size_t)(b * NSL + s) * KC + k] = a[k];
      }
    }
    __syncthreads();                       // exbuf ready
    if (t < NPTS) {
      float* __restrict__ pp = part + (size_t)(b * NSL + s) * KC * NPTS + t;
#pragma unroll
      for (int k = 0; k < KC; ++k)
        pp[(size_t)k * NPTS] = acc[k] + exbuf[t * KC + k];   // dims[0,32)+dims[32,64) halves
    }
  }
}

// ---------------- K3a/K3b: transpose [KC][DIMS] -> [DIMS][KC] via ws staging ----------------
__global__ __launch_bounds__(BLK) void k_stage(const float* __restrict__ cent,
                                               float* __restrict__ stage) {
  const int b = blockIdx.x >> 2, s = blockIdx.x & 3;
  const int t = threadIdx.x;
#pragma unroll
  for (int i = 0; i < 3; ++i) {
    const int e = t + BLK * i;
    const int k = e >> 9, cl = e & (SLD - 1);
    stage[(size_t)blockIdx.x * 3072 + e] =
        cent[((size_t)b * KC + k) * DIMS + s * SLD + cl];
  }
}

__global__ __launch_bounds__(BLK) void k_out(const float* __restrict__ stage,
                                             float* __restrict__ out) {
  const int b = blockIdx.x >> 2, s = blockIdx.x & 3;
  const int t = threadIdx.x;
#pragma unroll
  for (int i = 0; i < 3; ++i) {
    const int e  = t + BLK * i;
    const int cl = e / KC;
    const int k  = e - cl * KC;
    const int c  = s * SLD + cl;
    out[((size_t)b * DIMS + c) * KC + k] =
        stage[(size_t)blockIdx.x * 3072 + k * SLD + cl];
  }
}

extern "C" void kernel_launch(void* const* d_in, const int* in_sizes, int n_in,
                              void* d_out, int out_size, void* d_ws, size_t ws_size,
                              hipStream_t stream) {
  const float* x = (const float*)d_in[0];
  float* out     = (float*)d_out;
  const int nb   = in_sizes[0] / (DIMS * NPTS);   // 64

  float* cent  = out;                                       // centers live in d_out
  float* part  = (float*)d_ws;                              // nb*NSL*KC*NPTS floats
  float* csqp  = part + (size_t)nb * NSL * KC * NPTS;
  float* stage = part;                                      // reuse after last k_iter

  const dim3 grid(nb * NSL), blk(BLK);
  hipLaunchKernelGGL(k_init, grid, blk, 0, stream, x, cent);
  hipLaunchKernelGGL(k_dots, grid, blk, 0, stream, x, cent, part, csqp);
  for (int it = 0; it < N_IT; ++it) {
    hipLaunchKernelGGL(k_iter, grid, blk, 0, stream, x, cent, part, csqp,
                       (it < N_IT - 1) ? 1 : 0);
  }
  hipLaunchKernelGGL(k_stage, grid, blk, 0, stream, cent, stage);
  hipLaunchKernelGGL(k_out,   grid, blk, 0, stream, stage, out);
}

// Round 7
// 1880.469 us; speedup vs baseline: 33.8892x; 33.8892x over previous
//
#include <hip/hip_runtime.h>

#define NPTS 288
#define DIMS 2048
#define KC   6
#define N_IT 25
#define BLK  1024
#define NSL  4              // dim-slices per batch (1 block each)
#define SLD  (DIMS / NSL)   // 512 dims per slice
#define TD   64             // dims per tile
#define NT   (SLD / TD)     // 8 tiles per slice
#define TP   66             // tile row stride in words ([j][d] layout)

// ---------------- K0: init centers = first KC points ----------------
__global__ __launch_bounds__(BLK) void k_init(const float* __restrict__ x,
                                              float* __restrict__ cent) {
  const int b = blockIdx.x >> 2, s = blockIdx.x & 3;
  const int t = threadIdx.x;
  const float* __restrict__ Mb = x + (size_t)b * (DIMS * NPTS);
#pragma unroll
  for (int i = 0; i < 3; ++i) {
    const int e  = t + BLK * i;      // 0..3071 = KC*SLD
    const int k  = e >> 9;
    const int cl = e & (SLD - 1);
    const int c  = s * SLD + cl;
    cent[((size_t)b * KC + k) * DIMS + c] = Mb[(size_t)c * NPTS + k];
  }
}

// ---------------- K1: dots for the INITIAL centers (prologue only) ----------------
__global__ __launch_bounds__(BLK) void k_dots(const float* __restrict__ x,
                                              const float* __restrict__ cent,
                                              float* __restrict__ part,
                                              float* __restrict__ csqp) {
  const int b = blockIdx.x >> 2, s = blockIdx.x & 3;
  const int t = threadIdx.x, wv = t >> 6, lane = t & 63;
  const float* __restrict__ Mb = x + (size_t)b * (DIMS * NPTS);
  const float* __restrict__ cb = cent + (size_t)b * (KC * DIMS);

  __shared__ __attribute__((aligned(16))) float cs[KC][SLD];
  __shared__ float part_l[3][KC][NPTS];
#pragma unroll
  for (int i = 0; i < 3; ++i) {
    const int e = t + BLK * i;
    const int k = e >> 9, cl = e & (SLD - 1);
    cs[k][cl] = cb[(size_t)k * DIMS + s * SLD + cl];
  }
  __syncthreads();

  if (wv < 15) {
    const int g = wv / 5;
    const int q = t - g * 320;
    if (q < NPTS) {
      const int c0 = (g == 0) ? 0   : (g == 1 ? 172 : 344);
      const int c1 = (g == 0) ? 172 : (g == 1 ? 344 : 512);
      float acc[KC];
#pragma unroll
      for (int k = 0; k < KC; ++k) acc[k] = 0.f;
      const float* __restrict__ pb = Mb + (size_t)(s * SLD) * NPTS + q;
#pragma unroll 2
      for (int c = c0; c < c1; c += 4) {
        const float p0 = pb[(size_t)(c + 0) * NPTS];
        const float p1 = pb[(size_t)(c + 1) * NPTS];
        const float p2 = pb[(size_t)(c + 2) * NPTS];
        const float p3 = pb[(size_t)(c + 3) * NPTS];
#pragma unroll
        for (int k = 0; k < KC; ++k) {
          const float4 cv = *(const float4*)&cs[k][c];
          acc[k] += p0 * cv.x + p1 * cv.y + p2 * cv.z + p3 * cv.w;
        }
      }
#pragma unroll
      for (int k = 0; k < KC; ++k) part_l[g][k][q] = acc[k];
    }
  } else {
    float a[KC];
#pragma unroll
    for (int k = 0; k < KC; ++k) a[k] = 0.f;
#pragma unroll
    for (int i = 0; i < SLD / 64; ++i) {
#pragma unroll
      for (int k = 0; k < KC; ++k) {
        const float v = cs[k][lane + 64 * i];
        a[k] += v * v;
      }
    }
#pragma unroll
    for (int k = 0; k < KC; ++k) {
#pragma unroll
      for (int off = 32; off; off >>= 1) a[k] += __shfl_xor(a[k], off, 64);
    }
    if (lane == 0) {
#pragma unroll
      for (int k = 0; k < KC; ++k)
        csqp[(size_t)(b * NSL + s) * KC + k] = a[k];
    }
  }
  __syncthreads();

  if (t < NPTS) {
#pragma unroll
    for (int k = 0; k < KC; ++k)
      part[((size_t)(b * NSL + s) * KC + k) * NPTS + t] =
          part_l[0][k][t] + part_l[1][k][t] + part_l[2][k][t];
  }
}

// ---------------- K2: fully-fused iteration, ONE sweep of x ----------------
// per 64-dim tile: stage (prefetched) -> sums(old assign) -> update cs -> dots partial
//
// Round-5/6 lesson: at the default 8-waves/EU VGPR budget (64), the 18-deep
// prefetch + accumulators oversubscribed registers -> accumulator spill inside
// unrolled loops -> 4.7 GB scratch writes/dispatch. Two-sided fix:
//  (a) amdgpu_waves_per_eu(4,4): pin occupancy target to 1 block/CU (LDS forces
//      that anyway) -> VGPR cap 128, not a min-only hint like launch_bounds.
//  (b) split prefetch into two 9-reg groups issued at different phases
//      -> peak live set ~35 VGPRs, safe even under a 64 budget.
__global__
__attribute__((amdgpu_flat_work_group_size(BLK, BLK), amdgpu_waves_per_eu(4, 4)))
void k_iter(const float* __restrict__ x,
            float* __restrict__ cent,
            float* __restrict__ part,
            float* __restrict__ csqp,
            int do_dots) {
  const int b = blockIdx.x >> 2, s = blockIdx.x & 3;
  const int t = threadIdx.x, wv = t >> 6, lane = t & 63;
  const float* __restrict__ Mb = x + (size_t)b * (DIMS * NPTS);
  float* __restrict__ cb = cent + (size_t)b * (KC * DIMS);

  __shared__ __attribute__((aligned(16))) float cs[KC][SLD];   // 12,288 B
  __shared__ float tile[NPTS * TP];                            // 76,032 B  [j][d] stride 66
  __shared__ float pool[KC][TD][17];                           // 26,112 B  (exchange buf after loop)
  __shared__ __attribute__((aligned(16))) int assign_s[NPTS];  // 1,152 B
  __shared__ float csqh[KC];
  __shared__ int cnt_i[KC];

  float* exbuf = &pool[0][0][0];   // [NPTS][KC] after tile loop

  // ---- issue prefetch of tile 0 immediately (hides under argmin phase) ----
  float preA[9], preB[9];
  {
    const float* __restrict__ src = Mb + (size_t)(s * SLD) * NPTS;   // dt = 0, linear
#pragma unroll
    for (int i = 0; i < 9; ++i) preA[i] = src[t + BLK * i];
#pragma unroll
    for (int i = 0; i < 9; ++i) preB[i] = src[t + BLK * (i + 9)];
  }

  // old centers slice -> LDS
#pragma unroll
  for (int i = 0; i < 3; ++i) {
    const int e = t + BLK * i;
    const int k = e >> 9, cl = e & (SLD - 1);
    cs[k][cl] = cb[(size_t)k * DIMS + s * SLD + cl];
  }

  // ---- argmin phase (redundant per slice-block; fixed order = deterministic) ----
  if (t < KC) {
    const float* pc = csqp + (size_t)b * NSL * KC + t;
    csqh[t] = 0.5f * (pc[0] + pc[KC] + pc[2 * KC] + pc[3 * KC]);
    cnt_i[t] = 0;
  }
  __syncthreads();

  int myA = -1;
  if (t < NPTS) {
    const float* pp = part + (size_t)b * NSL * KC * NPTS + t;
    float best = 0.f;
    int bi = 0;
#pragma unroll
    for (int k = 0; k < KC; ++k) {
      const float S = pp[(size_t)k * NPTS] + pp[(size_t)(KC + k) * NPTS] +
                      pp[(size_t)(2 * KC + k) * NPTS] + pp[(size_t)(3 * KC + k) * NPTS];
      const float sc = csqh[k] - S;     // argmin_k(d) == argmin_k(csq/2 - S)
      if (k == 0 || sc < best) { best = sc; bi = k; }
    }
    assign_s[t] = bi;
    myA = bi;
  }
  if (t < 320) {   // waves 0..4, uniform per-wave predicate
#pragma unroll
    for (int k = 0; k < KC; ++k) {
      unsigned long long m = __ballot(myA == k);
      if (lane == 0) atomicAdd(&cnt_i[k], (int)__popcll(m));
    }
  }
  __syncthreads();   // assign + counts ready

  // hoist this wave's 18 point-assignments into SGPRs
  int aj[18];
#pragma unroll
  for (int r = 0; r < 18; ++r)
    aj[r] = __builtin_amdgcn_readfirstlane(assign_s[wv * 18 + r]);

  // dots state: waves 0-4 <-> points x dims[0,32); waves 5-9 <-> points x dims[32,64)
  const int grp  = wv / 5;                 // 0,1 active; 2,3 idle in dots
  const int dq   = t - grp * 320;          // point index for grp<2
  const bool dact = (wv < 10) && (dq < NPTS);
  float acc[KC];
#pragma unroll
  for (int k = 0; k < KC; ++k) acc[k] = 0.f;

  // ---- tile loop: ONE pass over x ----
  for (int dt = 0; dt < NT; ++dt) {
    __syncthreads();                       // (A) tile free (prev dots done reading)
#pragma unroll
    for (int i = 0; i < 9; ++i) {          // regs -> tile  [j][d] stride 66
      const int e = t + BLK * i;
      const int d = e / NPTS, j = e - d * NPTS;
      tile[j * TP + d] = preA[i];
    }
#pragma unroll
    for (int i = 0; i < 9; ++i) {
      const int e = t + BLK * (i + 9);
      const int d = e / NPTS, j = e - d * NPTS;
      tile[j * TP + d] = preB[i];
    }
    __syncthreads();                       // (B) tile ready

    if (dt + 1 < NT) {                     // prefetch group A (hides under sums)
      const float* __restrict__ src = Mb + (size_t)(s * SLD + (dt + 1) * TD) * NPTS;
#pragma unroll
      for (int i = 0; i < 9; ++i) preA[i] = src[t + BLK * i];
    }

    // sums: lane <-> dim, wave <-> 18 points; scalar branch on SGPR assignment
    {
      float s0 = 0, s1 = 0, s2 = 0, s3 = 0, s4 = 0, s5 = 0;
      const int jb = wv * 18;
#pragma unroll
      for (int r = 0; r < 18; ++r) {
        const float p = tile[(jb + r) * TP + lane];
        const int a = aj[r];
        if      (a == 0) s0 += p;
        else if (a == 1) s1 += p;
        else if (a == 2) s2 += p;
        else if (a == 3) s3 += p;
        else if (a == 4) s4 += p;
        else             s5 += p;
      }
      pool[0][lane][wv] = s0; pool[1][lane][wv] = s1; pool[2][lane][wv] = s2;
      pool[3][lane][wv] = s3; pool[4][lane][wv] = s4; pool[5][lane][wv] = s5;
    }
    __syncthreads();                       // (C) pool ready

    if (dt + 1 < NT) {                     // prefetch group B (hides under reduce+dots)
      const float* __restrict__ src = Mb + (size_t)(s * SLD + (dt + 1) * TD) * NPTS;
#pragma unroll
      for (int i = 0; i < 9; ++i) preB[i] = src[t + BLK * (i + 9)];
    }

    if (t < KC * TD) {                     // 384 threads: reduce 16 waves, update cs
      const int k = t >> 6, d = t & 63;
      float sum = 0.f;
#pragma unroll
      for (int w = 0; w < 16; ++w) sum += pool[k][d][w];   // fixed order
      const int cn = cnt_i[k];
      const int cl = dt * TD + d;
      cs[k][cl] = (cn > 0) ? (sum / (float)cn) : cs[k][cl];
    }
    __syncthreads();                       // (D) new cs for this tile ready

    // dots partial for these 64 dims from the SAME tile (new centers)
    if (do_dots && dact) {
      const int base = dq * TP + grp * 32;
      const int cbase = dt * TD + grp * 32;
#pragma unroll
      for (int db = 0; db < 8; ++db) {
        const float2 p01 = *(const float2*)&tile[base + db * 4];
        const float2 p23 = *(const float2*)&tile[base + db * 4 + 2];
#pragma unroll
        for (int k = 0; k < KC; ++k) {
          const float4 cv = *(const float4*)&cs[k][cbase + db * 4];  // uniform broadcast
          acc[k] += p01.x * cv.x + p01.y * cv.y + p23.x * cv.z + p23.y * cv.w;
        }
      }
    }
  }

  // store new centers (next dispatch + final output read them)
#pragma unroll
  for (int i = 0; i < 3; ++i) {
    const int e = t + BLK * i;
    const int k = e >> 9, cl = e & (SLD - 1);
    cb[(size_t)k * DIMS + s * SLD + cl] = cs[k][cl];
  }

  if (do_dots) {
    __syncthreads();                       // dots done; pool area free for exchange
    if (wv >= 5 && wv < 10 && dq < NPTS) {
#pragma unroll
      for (int k = 0; k < KC; ++k) exbuf[dq * KC + k] = acc[k];
    }
    if (wv == 15) {
      // csq of the NEW centers
      float a[KC];
#pragma unroll
      for (int k = 0; k < KC; ++k) a[k] = 0.f;
#pragma unroll
      for (int i = 0; i < SLD / 64; ++i) {
#pragma unroll
        for (int k = 0; k < KC; ++k) {
          const float v = cs[k][lane + 64 * i];
          a[k] += v * v;
        }
      }
#pragma unroll
      for (int k = 0; k < KC; ++k) {
#pragma unroll
        for (int off = 32; off; off >>= 1) a[k] += __shfl_xor(a[k], off, 64);
      }
      if (lane == 0) {
#pragma unroll
        for (int k = 0; k < KC; ++k)
          csqp[(size_t)(b * NSL + s) * KC + k] = a[k];
      }
    }
    __syncthreads();                       // exbuf ready
    if (t < NPTS) {
      float* __restrict__ pp = part + (size_t)(b * NSL + s) * KC * NPTS + t;
#pragma unroll
      for (int k = 0; k < KC; ++k)
        pp[(size_t)k * NPTS] = acc[k] + exbuf[t * KC + k];   // dims[0,32)+dims[32,64) halves
    }
  }
}

// ---------------- K3a/K3b: transpose [KC][DIMS] -> [DIMS][KC] via ws staging ----------------
__global__ __launch_bounds__(BLK) void k_stage(const float* __restrict__ cent,
                                               float* __restrict__ stage) {
  const int b = blockIdx.x >> 2, s = blockIdx.x & 3;
  const int t = threadIdx.x;
#pragma unroll
  for (int i = 0; i < 3; ++i) {
    const int e = t + BLK * i;
    const int k = e >> 9, cl = e & (SLD - 1);
    stage[(size_t)blockIdx.x * 3072 + e] =
        cent[((size_t)b * KC + k) * DIMS + s * SLD + cl];
  }
}

__global__ __launch_bounds__(BLK) void k_out(const float* __restrict__ stage,
                                             float* __restrict__ out) {
  const int b = blockIdx.x >> 2, s = blockIdx.x & 3;
  const int t = threadIdx.x;
#pragma unroll
  for (int i = 0; i < 3; ++i) {
    const int e  = t + BLK * i;
    const int cl = e / KC;
    const int k  = e - cl * KC;
    const int c  = s * SLD + cl;
    out[((size_t)b * DIMS + c) * KC + k] =
        stage[(size_t)blockIdx.x * 3072 + k * SLD + cl];
  }
}

extern "C" void kernel_launch(void* const* d_in, const int* in_sizes, int n_in,
                              void* d_out, int out_size, void* d_ws, size_t ws_size,
                              hipStream_t stream) {
  const float* x = (const float*)d_in[0];
  float* out     = (float*)d_out;
  const int nb   = in_sizes[0] / (DIMS * NPTS);   // 64

  float* cent  = out;                                       // centers live in d_out
  float* part  = (float*)d_ws;                              // nb*NSL*KC*NPTS floats
  float* csqp  = part + (size_t)nb * NSL * KC * NPTS;
  float* stage = part;                                      // reuse after last k_iter

  const dim3 grid(nb * NSL), blk(BLK);
  hipLaunchKernelGGL(k_init, grid, blk, 0, stream, x, cent);
  hipLaunchKernelGGL(k_dots, grid, blk, 0, stream, x, cent, part, csqp);
  for (int it = 0; it < N_IT; ++it) {
    hipLaunchKernelGGL(k_iter, grid, blk, 0, stream, x, cent, part, csqp,
                       (it < N_IT - 1) ? 1 : 0);
  }
  hipLaunchKernelGGL(k_stage, grid, blk, 0, stream, cent, stage);
  hipLaunchKernelGGL(k_out,   grid, blk, 0, stream, stage, out);
}

// Round 8
// 1697.625 us; speedup vs baseline: 37.5393x; 1.1077x over previous
//
#include <hip/hip_runtime.h>

#define NPTS 288
#define DIMS 2048
#define KC   6
#define N_IT 25
#define BLK  1024
#define NSL  8              // dim-slices per batch (1 block each) -> 512 blocks = 2/CU
#define SLD  (DIMS / NSL)   // 256 dims per slice
#define TD   64             // dims per sums-tile
#define NT   (SLD / TD)     // 4 sums-tiles per slice
#define CPB  (KC * SLD)     // 1536 center elems per block

// ---------------- K0: init centers = first KC points ----------------
__global__ __launch_bounds__(BLK) void k_init(const float* __restrict__ x,
                                              float* __restrict__ cent) {
  const int b = blockIdx.x >> 3, s = blockIdx.x & 7;
  const int t = threadIdx.x;
  const float* __restrict__ Mb = x + (size_t)b * (DIMS * NPTS);
#pragma unroll
  for (int i = 0; i < 2; ++i) {
    const int e = t + BLK * i;       // 0..2047, need < 1536
    if (e < CPB) {
      const int k  = e >> 8;         // e / SLD
      const int cl = e & (SLD - 1);
      const int c  = s * SLD + cl;
      cent[((size_t)b * KC + k) * DIMS + c] = Mb[(size_t)c * NPTS + k];
    }
  }
}

// ---------------- K1: iteration kernel ----------------
// do_sums: argmin (from prev dots) + LDS-staged sums + center update
// do_dots: distance dot-products for the (possibly updated) centers, global reads
// 71 KB LDS -> 2 blocks/CU: co-resident blocks overlap mem/LDS/VALU phases.
__global__ __launch_bounds__(BLK) void k_iter(const float* __restrict__ x,
                                              float* __restrict__ cent,
                                              float* __restrict__ part,
                                              float* __restrict__ csqp,
                                              int do_sums, int do_dots) {
  const int b = blockIdx.x >> 3, s = blockIdx.x & 7;
  const int t = threadIdx.x, wv = t >> 6, lane = t & 63;
  const float* __restrict__ Mb = x + (size_t)b * (DIMS * NPTS);
  float* __restrict__ cb = cent + (size_t)b * (KC * DIMS);

  __shared__ __attribute__((aligned(16))) float cs[KC][SLD];   //  6,144 B
  __shared__ float tile[TD * 145];                             // 37,120 B [d][j] pad 145
  __shared__ __attribute__((aligned(16))) char upool[26112];   // pool / part_l union
  __shared__ __attribute__((aligned(16))) int assign_s[NPTS];  //  1,152 B
  __shared__ float csqh[KC];
  __shared__ int cnt_i[KC];

  float (*pool)[TD][17]     = (float (*)[TD][17])(void*)upool;     // [KC][64][17]
  float (*part_l)[KC][NPTS] = (float (*)[KC][NPTS])(void*)upool;   // [3][KC][NPTS]

  // centers slice -> LDS
#pragma unroll
  for (int i = 0; i < 2; ++i) {
    const int e = t + BLK * i;
    if (e < CPB) {
      const int k = e >> 8, cl = e & (SLD - 1);
      cs[k][cl] = cb[(size_t)k * DIMS + s * SLD + cl];
    }
  }

  if (do_sums) {
    // ---- argmin (redundant per slice-block; fixed order = deterministic) ----
    if (t < KC) {
      const float* pc = csqp + (size_t)b * NSL * KC + t;
      float cq = 0.f;
#pragma unroll
      for (int g = 0; g < NSL; ++g) cq += pc[g * KC];
      csqh[t] = 0.5f * cq;
      cnt_i[t] = 0;
    }
    __syncthreads();

    int myA = -1;
    if (t < NPTS) {
      const float* pp = part + (size_t)b * NSL * KC * NPTS + t;
      float best = 0.f;
      int bi = 0;
#pragma unroll
      for (int k = 0; k < KC; ++k) {
        float S = 0.f;
#pragma unroll
        for (int g = 0; g < NSL; ++g) S += pp[(size_t)(g * KC + k) * NPTS];
        const float sc = csqh[k] - S;     // argmin_k(d) == argmin_k(csq/2 - S)
        if (k == 0 || sc < best) { best = sc; bi = k; }
      }
      assign_s[t] = bi;
      myA = bi;
    }
    if (t < 320) {   // waves 0..4, uniform per-wave predicate
#pragma unroll
      for (int k = 0; k < KC; ++k) {
        unsigned long long m = __ballot(myA == k);
        if (lane == 0) atomicAdd(&cnt_i[k], (int)__popcll(m));
      }
    }
    __syncthreads();   // assign + counts ready

    // hoist this wave's 18 point-assignments into SGPRs (wave-uniform)
    int aj[2][9];
#pragma unroll
    for (int h = 0; h < 2; ++h)
#pragma unroll
      for (int r = 0; r < 9; ++r)
        aj[h][r] = __builtin_amdgcn_readfirstlane(assign_s[h * 144 + wv * 9 + r]);

    // ---- sums sweep: 4 dim-tiles x 2 point-halves; wave = 64 lanes <-> 64 dims ----
    for (int dt = 0; dt < NT; ++dt) {
      float s0 = 0, s1 = 0, s2 = 0, s3 = 0, s4 = 0, s5 = 0;
#pragma unroll
      for (int h = 0; h < 2; ++h) {
        __syncthreads();                     // tile region free
#pragma unroll
        for (int i = 0; i < 9; ++i) {        // stage [64][144] coalesced
          const int e = t + BLK * i;         // 0..9215
          const int d = e / 144, j = e - d * 144;
          tile[d * 145 + j] = Mb[(size_t)(s * SLD + dt * TD + d) * NPTS + h * 144 + j];
        }
        __syncthreads();                     // staged
        const int base = lane * 145 + wv * 9;  // lane <-> dim, wave <-> 9-pt group
#pragma unroll
        for (int r = 0; r < 9; ++r) {
          const float p = tile[base + r];
          const int a = aj[h][r];            // SGPR -> scalar branch, body = 1 v_add
          if      (a == 0) s0 += p;
          else if (a == 1) s1 += p;
          else if (a == 2) s2 += p;
          else if (a == 3) s3 += p;
          else if (a == 4) s4 += p;
          else             s5 += p;
        }
      }
      pool[0][lane][wv] = s0; pool[1][lane][wv] = s1; pool[2][lane][wv] = s2;
      pool[3][lane][wv] = s3; pool[4][lane][wv] = s4; pool[5][lane][wv] = s5;
      __syncthreads();                       // pool ready
      if (t < KC * TD) {                     // reduce 16 waves, update cs
        const int k = t >> 6, d = t & 63;
        float sum = 0.f;
#pragma unroll
        for (int w = 0; w < 16; ++w) sum += pool[k][d][w];   // fixed order
        const int cn = cnt_i[k];
        const int cl = dt * TD + d;
        cs[k][cl] = (cn > 0) ? (sum / (float)cn) : cs[k][cl];
      }
    }

    // store new centers (next dispatch + final output read them)
    __syncthreads();                         // cs updates complete
#pragma unroll
    for (int i = 0; i < 2; ++i) {
      const int e = t + BLK * i;
      if (e < CPB) {
        const int k = e >> 8, cl = e & (SLD - 1);
        cb[(size_t)k * DIMS + s * SLD + cl] = cs[k][cl];
      }
    }
  }

  if (!do_dots) return;
  __syncthreads();   // cs final + pool/part_l region free (uniform barrier)

  // ---- dots: 3 dim-groups x 5 waves, lanes <-> points; global coalesced reads ----
  if (wv < 15) {
    const int g = wv / 5;
    const int q = t - g * 320;
    if (q < NPTS) {
      const int c0 = (g == 0) ? 0  : (g == 1 ? 88  : 176);
      const int c1 = (g == 0) ? 88 : (g == 1 ? 176 : SLD);
      float acc[KC];
#pragma unroll
      for (int k = 0; k < KC; ++k) acc[k] = 0.f;
      const float* __restrict__ pb = Mb + (size_t)(s * SLD) * NPTS + q;
#pragma unroll 2
      for (int c = c0; c < c1; c += 4) {
        const float p0 = pb[(size_t)(c + 0) * NPTS];   // coalesced across lanes
        const float p1 = pb[(size_t)(c + 1) * NPTS];
        const float p2 = pb[(size_t)(c + 2) * NPTS];
        const float p3 = pb[(size_t)(c + 3) * NPTS];
#pragma unroll
        for (int k = 0; k < KC; ++k) {
          const float4 cv = *(const float4*)&cs[k][c];  // wave-uniform LDS broadcast
          acc[k] += p0 * cv.x + p1 * cv.y + p2 * cv.z + p3 * cv.w;
        }
      }
#pragma unroll
      for (int k = 0; k < KC; ++k) part_l[g][k][q] = acc[k];
    }
  } else {
    // wave 15: csq partial of the current centers over this slice
    float a[KC];
#pragma unroll
    for (int k = 0; k < KC; ++k) a[k] = 0.f;
#pragma unroll
    for (int i = 0; i < SLD / 64; ++i) {
#pragma unroll
      for (int k = 0; k < KC; ++k) {
        const float v = cs[k][lane + 64 * i];
        a[k] += v * v;
      }
    }
#pragma unroll
    for (int k = 0; k < KC; ++k) {
#pragma unroll
      for (int off = 32; off; off >>= 1) a[k] += __shfl_xor(a[k], off, 64);
    }
    if (lane == 0) {
#pragma unroll
      for (int k = 0; k < KC; ++k)
        csqp[(size_t)(b * NSL + s) * KC + k] = a[k];
    }
  }
  __syncthreads();   // group partials ready

  if (t < NPTS) {    // reduce 3 dim-groups, fixed order
#pragma unroll
    for (int k = 0; k < KC; ++k)
      part[((size_t)(b * NSL + s) * KC + k) * NPTS + t] =
          part_l[0][k][t] + part_l[1][k][t] + part_l[2][k][t];
  }
}

// ---------------- K2a/K2b: transpose [KC][DIMS] -> [DIMS][KC] via ws staging ----------------
__global__ __launch_bounds__(BLK) void k_stage(const float* __restrict__ cent,
                                               float* __restrict__ stage) {
  const int b = blockIdx.x >> 3, s = blockIdx.x & 7;
  const int t = threadIdx.x;
#pragma unroll
  for (int i = 0; i < 2; ++i) {
    const int e = t + BLK * i;
    if (e < CPB) {
      const int k = e >> 8, cl = e & (SLD - 1);
      stage[(size_t)blockIdx.x * CPB + e] =
          cent[((size_t)b * KC + k) * DIMS + s * SLD + cl];
    }
  }
}

__global__ __launch_bounds__(BLK) void k_out(const float* __restrict__ stage,
                                             float* __restrict__ out) {
  const int b = blockIdx.x >> 3, s = blockIdx.x & 7;
  const int t = threadIdx.x;
#pragma unroll
  for (int i = 0; i < 2; ++i) {
    const int e = t + BLK * i;
    if (e < CPB) {
      const int cl = e / KC;              // 0..255
      const int k  = e - cl * KC;
      const int c  = s * SLD + cl;
      out[((size_t)b * DIMS + c) * KC + k] =
          stage[(size_t)blockIdx.x * CPB + k * SLD + cl];
    }
  }
}

extern "C" void kernel_launch(void* const* d_in, const int* in_sizes, int n_in,
                              void* d_out, int out_size, void* d_ws, size_t ws_size,
                              hipStream_t stream) {
  const float* x = (const float*)d_in[0];
  float* out     = (float*)d_out;
  const int nb   = in_sizes[0] / (DIMS * NPTS);   // 64

  float* cent  = out;                                       // centers live in d_out
  float* part  = (float*)d_ws;                              // nb*NSL*KC*NPTS floats (14.2 MB)
  float* csqp  = part + (size_t)nb * NSL * KC * NPTS;
  float* stage = part;                                      // reuse after last k_iter

  const dim3 grid(nb * NSL), blk(BLK);
  hipLaunchKernelGGL(k_init, grid, blk, 0, stream, x, cent);
  // prologue: dots only (initial centers)
  hipLaunchKernelGGL(k_iter, grid, blk, 0, stream, x, cent, part, csqp, 0, 1);
  // 25 updates; last one skips the dots
  for (int it = 0; it < N_IT; ++it) {
    hipLaunchKernelGGL(k_iter, grid, blk, 0, stream, x, cent, part, csqp,
                       1, (it < N_IT - 1) ? 1 : 0);
  }
  hipLaunchKernelGGL(k_stage, grid, blk, 0, stream, cent, stage);
  hipLaunchKernelGGL(k_out,   grid, blk, 0, stream, stage, out);
}

// Round 9
// 638.679 us; speedup vs baseline: 99.7803x; 2.6580x over previous
//
#include <hip/hip_runtime.h>

#define NPTS 288
#define DIMS 2048
#define KC   6
#define N_IT 25

// ---------------- k_gram: G[b] = A^T A  (A = x[b], 2048 x 288) ----------------
// grid nb*9, block 256.  Tile 96x96 (3x3 tile grid, no padding: 3*96=288),
// micro 6x6 per thread (16x16 thread grid), K-chunk 32.
#define GT 96
#define KB 32
#define GP 100    // padded LDS row in floats

__global__ __launch_bounds__(256, 2) void k_gram(const float* __restrict__ x,
                                                 float* __restrict__ G, int nb) {
  const int bid = blockIdx.x;
  const int b = bid / 9, pr = bid - b * 9;
  const int ti = pr / 3, tj = pr - ti * 3;
  const int t = threadIdx.x;
  const int tr = t >> 4, tc = t & 15;
  const float* __restrict__ xb = x + (size_t)b * (DIMS * NPTS);
  float* __restrict__ Gb = G + (size_t)b * (NPTS * NPTS);

  __shared__ float Ai[KB][GP];   // 12.8 KB
  __shared__ float Aj[KB][GP];   // 12.8 KB

  float acc[6][6];
#pragma unroll
  for (int ii = 0; ii < 6; ++ii)
#pragma unroll
    for (int jj = 0; jj < 6; ++jj) acc[ii][jj] = 0.f;

  for (int k0 = 0; k0 < DIMS; k0 += KB) {
    __syncthreads();
#pragma unroll
    for (int q = 0; q < 12; ++q) {          // 3072 elems per panel / 256 thr
      const int e  = t + 256 * q;
      const int kk = e / GT, i = e - kk * GT;
      Ai[kk][i] = xb[(size_t)(k0 + kk) * NPTS + ti * GT + i];   // coalesced 96-runs
      Aj[kk][i] = xb[(size_t)(k0 + kk) * NPTS + tj * GT + i];
    }
    __syncthreads();
#pragma unroll
    for (int kk = 0; kk < KB; ++kk) {
      float af[6], bf[6];
      const float2 a01 = *(const float2*)&Ai[kk][6 * tr];
      const float2 a23 = *(const float2*)&Ai[kk][6 * tr + 2];
      const float2 a45 = *(const float2*)&Ai[kk][6 * tr + 4];
      const float2 b01 = *(const float2*)&Aj[kk][6 * tc];
      const float2 b23 = *(const float2*)&Aj[kk][6 * tc + 2];
      const float2 b45 = *(const float2*)&Aj[kk][6 * tc + 4];
      af[0] = a01.x; af[1] = a01.y; af[2] = a23.x; af[3] = a23.y; af[4] = a45.x; af[5] = a45.y;
      bf[0] = b01.x; bf[1] = b01.y; bf[2] = b23.x; bf[3] = b23.y; bf[4] = b45.x; bf[5] = b45.y;
#pragma unroll
      for (int ii = 0; ii < 6; ++ii)
#pragma unroll
        for (int jj = 0; jj < 6; ++jj) acc[ii][jj] += af[ii] * bf[jj];
    }
  }

#pragma unroll
  for (int ii = 0; ii < 6; ++ii) {
    const int ri = ti * GT + 6 * tr + ii;
#pragma unroll
    for (int jj = 0; jj < 6; ++jj)
      Gb[(size_t)ri * NPTS + tj * GT + 6 * tc + jj] = acc[ii][jj];
  }
}

// ---------------- k_lloyd: all 25 Lloyd iterations on G ----------------
// grid nb, block 1024. Centers = weight vectors w over points (LDS, [j][8] pad).
__global__ __launch_bounds__(1024) void k_lloyd(const float* __restrict__ G,
                                                float* __restrict__ wg, int nb) {
  const int b = blockIdx.x;
  const int t = threadIdx.x, wv = t >> 6, lane = t & 63;
  const float* __restrict__ Gb = G + (size_t)b * (NPTS * NPTS);

  __shared__ float w2[NPTS][8];          //  9.2 KB  weights [point][k], pad 8
  __shared__ float pool[KC][NPTS][5];    // 34.6 KB  u partials (3 used, pad 5)
  __shared__ float u[KC][NPTS];          //  6.9 KB  u[k][i] = p_i . c_k
  __shared__ int assign_s[NPTS];
  __shared__ float csq[KC];
  __shared__ int cnt_i[KC];

  // init: w_k = e_k  (centers0 = first KC points)
  for (int e = t; e < NPTS * 8; e += 1024) {
    const int i = e >> 3, k = e & 7;
    w2[i][k] = (k < KC && i == k) ? 1.f : 0.f;
  }
  __syncthreads();

  for (int it = 0; it < N_IT; ++it) {
    // ---- u = G * w : waves 0-14, jg = point-column third, lanes <-> rows ----
    {
      const int jg = t / 320;              // wave-uniform (320 = 5 waves)
      const int i  = t - jg * 320;
      if (t < 960 && i < NPTS) {
        float a0 = 0, a1 = 0, a2 = 0, a3 = 0, a4 = 0, a5 = 0;
        const float* __restrict__ gp = Gb + (size_t)(jg * 96) * NPTS + i;
        for (int jj = 0; jj < 96; ++jj) {
          const float g = gp[(size_t)jj * NPTS];            // coalesced (rows of G)
          const int j = jg * 96 + jj;
          const float4 wA = *(const float4*)&w2[j][0];      // uniform broadcast
          const float2 wB = *(const float2*)&w2[j][4];
          a0 += wA.x * g; a1 += wA.y * g; a2 += wA.z * g;
          a3 += wA.w * g; a4 += wB.x * g; a5 += wB.y * g;
        }
        pool[0][i][jg] = a0; pool[1][i][jg] = a1; pool[2][i][jg] = a2;
        pool[3][i][jg] = a3; pool[4][i][jg] = a4; pool[5][i][jg] = a5;
      }
    }
    __syncthreads();
    // ---- u reduce (fixed order) ----
    for (int e = t; e < KC * NPTS; e += 1024) {
      const int k = e / NPTS, i = e - k * NPTS;
      u[k][i] = pool[k][i][0] + pool[k][i][1] + pool[k][i][2];
    }
    if (t >= 960 && t < 960 + KC) cnt_i[t - 960] = 0;   // wave 15: reset counts
    __syncthreads();
    // ---- csq_k = w_k^T u_k : wave k, lane-strided + shuffle tree (fixed order) ----
    if (wv < KC) {
      float s = 0.f;
      for (int i = lane; i < NPTS; i += 64) s += w2[i][wv] * u[wv][i];
#pragma unroll
      for (int off = 32; off; off >>= 1) s += __shfl_xor(s, off, 64);
      if (lane == 0) csq[wv] = s;
    }
    __syncthreads();
    // ---- scores + argmin + counts ----
    int myA = -1;
    if (t < NPTS) {
      float best = 0.f;
      int bi = 0;
#pragma unroll
      for (int k = 0; k < KC; ++k) {
        const float sc = 0.5f * csq[k] - u[k][t];   // argmin_k(dist) equivalent
        if (k == 0 || sc < best) { best = sc; bi = k; }   // strict < : first-min
      }
      assign_s[t] = bi;
      myA = bi;
    }
    if (t < 320) {   // waves 0-4, uniform predicate; int atomics: deterministic
#pragma unroll
      for (int k = 0; k < KC; ++k) {
        unsigned long long m = __ballot(myA == k);
        if (lane == 0) atomicAdd(&cnt_i[k], (int)__popcll(m));
      }
    }
    __syncthreads();
    // ---- w update: live clusters get a_k/n_k, empty keep old weights ----
    if (t < NPTS) {
      const int a = assign_s[t];
#pragma unroll
      for (int k = 0; k < KC; ++k) {
        const int cn = cnt_i[k];
        if (cn > 0) w2[t][k] = (a == k) ? (1.0f / (float)cn) : 0.f;
      }
    }
    __syncthreads();
  }

  // final weights -> global (k_cent consumes them)
  for (int e = t; e < NPTS * 8; e += 1024)
    wg[(size_t)b * (NPTS * 8) + e] = w2[e >> 3][e & 7];
}

// ---------------- k_cent: out[b][c][k] = sum_j w[k][j] * x[b][c][j] ----------------
// grid nb*8 (8 dim-slices of 256), block 1024. Round-8 staged-tile machinery.
__global__ __launch_bounds__(1024) void k_cent(const float* __restrict__ x,
                                               const float* __restrict__ wg,
                                               float* __restrict__ out, int nb) {
  const int b = blockIdx.x >> 3, s = blockIdx.x & 7;
  const int t = threadIdx.x, wv = t >> 6, lane = t & 63;
  const float* __restrict__ Mb = x + (size_t)b * (DIMS * NPTS);

  __shared__ float tile[64 * 145];       // 37.1 KB  [d][j] pad 145
  __shared__ float pool[KC][64][17];     // 26.1 KB
  __shared__ float w2[NPTS][8];          //  9.2 KB

  for (int e = t; e < NPTS * 8; e += 1024)
    w2[e >> 3][e & 7] = wg[(size_t)b * (NPTS * 8) + e];

  for (int dt = 0; dt < 4; ++dt) {
    float a0 = 0, a1 = 0, a2 = 0, a3 = 0, a4 = 0, a5 = 0;
#pragma unroll
    for (int h = 0; h < 2; ++h) {
      __syncthreads();                   // tile free (also covers w2 staging, dt=0)
#pragma unroll
      for (int i = 0; i < 9; ++i) {      // stage [64 d][144 j] coalesced
        const int e = t + 1024 * i;      // 0..9215
        const int d = e / 144, j = e - d * 144;
        tile[d * 145 + j] = Mb[(size_t)(s * 256 + dt * 64 + d) * NPTS + h * 144 + j];
      }
      __syncthreads();
      const int base = lane * 145 + wv * 9;   // lane <-> dim, wave <-> 9-pt group
#pragma unroll
      for (int r = 0; r < 9; ++r) {
        const float p = tile[base + r];
        const int j = h * 144 + wv * 9 + r;
        const float4 wA = *(const float4*)&w2[j][0];    // uniform broadcast
        const float2 wB = *(const float2*)&w2[j][4];
        a0 += wA.x * p; a1 += wA.y * p; a2 += wA.z * p;
        a3 += wA.w * p; a4 += wB.x * p; a5 += wB.y * p;
      }
    }
    pool[0][lane][wv] = a0; pool[1][lane][wv] = a1; pool[2][lane][wv] = a2;
    pool[3][lane][wv] = a3; pool[4][lane][wv] = a4; pool[5][lane][wv] = a5;
    __syncthreads();
    if (t < KC * 64) {                   // t = d*6 + k  -> coalesced 1536-B output run
      const int d = t / KC, k = t - d * KC;
      float sum = 0.f;
#pragma unroll
      for (int w = 0; w < 16; ++w) sum += pool[k][d][w];   // fixed order
      out[((size_t)b * DIMS + s * 256 + dt * 64 + d) * KC + k] = sum;
    }
    __syncthreads();                     // pool/out read done before next dt reuses
  }
}

extern "C" void kernel_launch(void* const* d_in, const int* in_sizes, int n_in,
                              void* d_out, int out_size, void* d_ws, size_t ws_size,
                              hipStream_t stream) {
  const float* x = (const float*)d_in[0];
  float* out     = (float*)d_out;
  const int nb   = in_sizes[0] / (DIMS * NPTS);   // 64

  float* G  = (float*)d_ws;                        // nb*288*288 floats = 21.2 MB
  float* wg = G + (size_t)nb * NPTS * NPTS;        // nb*288*8 floats

  hipLaunchKernelGGL(k_gram,  dim3(nb * 9), dim3(256),  0, stream, x, G, nb);
  hipLaunchKernelGGL(k_lloyd, dim3(nb),     dim3(1024), 0, stream, G, wg, nb);
  hipLaunchKernelGGL(k_cent,  dim3(nb * 8), dim3(1024), 0, stream, x, wg, out, nb);
}